// Round 3
// baseline (431.702 us; speedup 1.0000x reference)
//
#include <hip/hip_runtime.h>
#include <math.h>

// SPMoEAdaptor: fused 2-layer soft-MoE + residual, N=524288, D=64, E=4.
// out = x + MoE_b(MoE_a(x));  MoE(v) = sum_e softmax(v@Wg)[e] * (v@W_e - b_e@W_e)
//
// R6 change: kill the spills for real. R4 (__launch_bounds__(1024,4)) and
// R5 (__launch_bounds__(1024)) BOTH compiled to 64 VGPR: for 1024-thread
// workgroups the allocator targets 8 waves/EU (512-reg file / 8 = 64) on its
// own and spills acc[4][4][4] to scratch (+490 MB HBM, hbm_bytes 7.6e8).
// It ignores that our 141KB LDS caps runtime occupancy at 1 WG/CU = 4
// waves/EU. Fix: __attribute__((amdgpu_waves_per_eu(4,4))) pins the budget
// at 512/4 = 128 VGPR; natural usage ~104 -> no spill, occupancy unchanged.
// Structure kept: 256 blocks x 16 waves sharing ONE weight image per CU.
//
// DTYPE-ADAPTIVE, in-kernel (no cross-kernel flag handoff): every block
// classifies each input buffer (bf16 vs fp32) by sampling 64 even-indexed
// uint16s; output dtype follows x's dtype. (R0-R3 forensics preserved.)
//
// MFMA 16x16x32_bf16 layouts (m89/m91): A: row=lane&15, k=(lane>>4)*8+j ;
// B: col=lane&15, same k ; C: col=lane&15, row=(lane>>4)*4+reg.

typedef __attribute__((ext_vector_type(8))) short short8;
typedef __attribute__((ext_vector_type(4))) short short4v;
typedef __attribute__((ext_vector_type(4))) float floatx4;

__device__ __forceinline__ float bf2f(unsigned short s) {
    unsigned int u = ((unsigned int)s) << 16;
    return __builtin_bit_cast(float, u);
}
__device__ __forceinline__ short f2bf(float f) {
    unsigned int u = __builtin_bit_cast(unsigned int, f);
    u += 0x7fffu + ((u >> 16) & 1u);   // RNE
    return (short)(u >> 16);
}

#define NBLOCKS 256
#define NTHREADS 1024
#define WPB 16   // waves per block
#define TPW 2    // tiles (of 64 tokens) per wave: 256*16*2*64 = 524288

__device__ __forceinline__ float ldf(const void* p, int isbf, int idx) {
    return isbf ? bf2f(((const unsigned short*)p)[idx]) : ((const float*)p)[idx];
}

__global__ __launch_bounds__(NTHREADS)
__attribute__((amdgpu_waves_per_eu(4, 4)))
void moe2_fused(const void* __restrict__ x,
                const void* __restrict__ wg_a,
                const void* __restrict__ we_a,
                const void* __restrict__ be_a,
                const void* __restrict__ wg_b,
                const void* __restrict__ we_b,
                const void* __restrict__ be_b,
                void* __restrict__ outv)
{
    __shared__ alignas(16) short sB[2][17408];     // weights, fragment-major bf16 (69632 B)
    __shared__ float sC[2][4][64];                 // c_e[f] = b_e @ W_e (2048 B)
    __shared__ alignas(16) float sScr[WPB][1088];  // per-wave scratch 4352 B (69632 B total)
    __shared__ int sBad[7];

    const int tid = threadIdx.x;

    // ---- in-block dtype classification (ballot-free, 256B/buffer) ----
    const void* ps[7] = {x, wg_a, we_a, be_a, wg_b, we_b, be_b};
    if (tid < 7) sBad[tid] = 0;
    __syncthreads();
    if (tid < 64) {
        #pragma unroll
        for (int b = 0; b < 7; ++b) {
            const unsigned short s = ((const unsigned short*)ps[b])[2 * tid];
            const float a = fabsf(bf2f(s));
            const bool sane = (s == 0) || (a >= 9.3e-10f && a <= 1.1e9f);
            if (!sane) atomicAdd(&sBad[b], 1);
        }
    }
    __syncthreads();
    const int fx  = (sBad[0] < 16);
    const int fga = (sBad[1] < 16), fwa = (sBad[2] < 16), fba = (sBad[3] < 16);
    const int fgb = (sBad[4] < 16), fwb = (sBad[5] < 16), fbb = (sBad[6] < 16);

    // ---- stage weights into LDS (-> bf16), fragment-major ----
    for (int idx = tid; idx < 2 * 17 * 2 * 64; idx += NTHREADS) {
        const int L   = idx / 2176;
        const int rem = idx - L * 2176;        // (t*2+kap)*64 + lane
        const int t   = rem >> 7;
        const int kap = (rem >> 6) & 1;
        const int l2  = rem & 63;
        const int kb  = kap * 32 + (l2 >> 4) * 8;
        const int cc  = l2 & 15;
        const void* we = L ? we_b : we_a;
        const void* wg = L ? wg_b : wg_a;
        const int  fwe = L ? fwb : fwa;
        const int  fwg = L ? fgb : fga;
        short* dst = &sB[L][rem * 8];
        if (t < 16) {
            const int e = t >> 2;
            const int f = (t & 3) * 16 + cc;
            #pragma unroll
            for (int j = 0; j < 8; ++j)
                dst[j] = f2bf(ldf(we, fwe, (e * 64 + kb + j) * 64 + f));  // w_exp[e][k][f]
        } else {  // gate tile: cols 0..3 = Wg, rest zero
            #pragma unroll
            for (int j = 0; j < 8; ++j)
                dst[j] = (cc < 4) ? f2bf(ldf(wg, fwg, (kb + j) * 4 + cc)) : (short)0;
        }
    }
    // ---- c_e[f] = sum_d b_e[d] * W_e[d][f] (fp32) ----
    for (int idx = tid; idx < 512; idx += NTHREADS) {
        const int L = idx >> 8;
        const int e = (idx >> 6) & 3;
        const int f = idx & 63;
        const void* we = L ? we_b : we_a;
        const void* be = L ? be_b : be_a;
        const int  fwe = L ? fwb : fwa;
        const int  fbe = L ? fbb : fba;
        float s = 0.f;
        for (int d = 0; d < 64; ++d)
            s += ldf(be, fbe, e * 64 + d) * ldf(we, fwe, (e * 64 + d) * 64 + f);
        sC[L][e][f] = s;
    }
    __syncthreads();

    const int l  = tid & 63;
    const int wv = tid >> 6;
    const int c  = l & 15;   // C-layout col AND A-layout row for this lane
    const int q  = l >> 4;
    float* stf = &sScr[wv][0];          // wave-private fp32 view
    short* stg = (short*)stf;           // wave-private bf16 view (no barriers needed)

    auto runLayer = [&](const short8 (&aF)[4][2], const int L, float (&acc)[4][4][4]) {
        const short* BL = &sB[L][0];
        floatx4 gA[4];
        {
            const short8 B0 = *(const short8*)&BL[(16 * 2 + 0) * 512 + l * 8];
            const short8 B1 = *(const short8*)&BL[(16 * 2 + 1) * 512 + l * 8];
            #pragma unroll
            for (int s = 0; s < 4; ++s) {
                floatx4 z = {0.f, 0.f, 0.f, 0.f};
                z = __builtin_amdgcn_mfma_f32_16x16x32_bf16(aF[s][0], B0, z, 0, 0, 0);
                z = __builtin_amdgcn_mfma_f32_16x16x32_bf16(aF[s][1], B1, z, 0, 0, 0);
                gA[s] = z;
            }
        }
        // softmax over 4 experts per row; stage g as bf16 [s][e][16 rows]
        #pragma unroll
        for (int s = 0; s < 4; ++s) {
            float lg[4][4];
            #pragma unroll
            for (int e = 0; e < 4; ++e)
                #pragma unroll
                for (int r = 0; r < 4; ++r)
                    lg[e][r] = __shfl(gA[s][r], (l & 48) + e, 64);
            short gv[4];
            #pragma unroll
            for (int r = 0; r < 4; ++r) {
                const float m0 = fmaxf(fmaxf(lg[0][r], lg[1][r]), fmaxf(lg[2][r], lg[3][r]));
                const float e0 = __expf(lg[0][r] - m0);
                const float e1 = __expf(lg[1][r] - m0);
                const float e2 = __expf(lg[2][r] - m0);
                const float e3 = __expf(lg[3][r] - m0);
                const float inv = 1.f / (e0 + e1 + e2 + e3);
                const float mine = (c == 0) ? e0 : (c == 1) ? e1 : (c == 2) ? e2 : e3;
                gv[r] = f2bf(mine * inv);
            }
            if (c < 4) {
                short4v pk = {gv[0], gv[1], gv[2], gv[3]};
                *(short4v*)&stg[(s * 4 + c) * 16 + 4 * q] = pk;
            }
        }

        #pragma unroll
        for (int s = 0; s < 4; ++s)
            #pragma unroll
            for (int tt = 0; tt < 4; ++tt)
                #pragma unroll
                for (int r = 0; r < 4; ++r)
                    acc[s][tt][r] = 0.f;

        #pragma unroll
        for (int e = 0; e < 4; ++e) {
            float gse[4][4];
            #pragma unroll
            for (int s = 0; s < 4; ++s) {
                const short4v gp = *(const short4v*)&stg[(s * 4 + e) * 16 + 4 * q];
                #pragma unroll
                for (int r = 0; r < 4; ++r)
                    gse[s][r] = bf2f((unsigned short)gp[r]);
            }
            #pragma unroll
            for (int tt = 0; tt < 4; ++tt) {
                const int t = e * 4 + tt;
                const short8 B0 = *(const short8*)&BL[(t * 2 + 0) * 512 + l * 8];
                const short8 B1 = *(const short8*)&BL[(t * 2 + 1) * 512 + l * 8];
                const float ce = sC[L][e][tt * 16 + c];
                #pragma unroll
                for (int s = 0; s < 4; ++s) {
                    floatx4 z = {0.f, 0.f, 0.f, 0.f};
                    z = __builtin_amdgcn_mfma_f32_16x16x32_bf16(aF[s][0], B0, z, 0, 0, 0);
                    z = __builtin_amdgcn_mfma_f32_16x16x32_bf16(aF[s][1], B1, z, 0, 0, 0);
                    #pragma unroll
                    for (int r = 0; r < 4; ++r)
                        acc[s][tt][r] += gse[s][r] * (z[r] - ce);
                }
            }
        }
    };

    const int waveGlobal = blockIdx.x * WPB + wv;
    for (int it = 0; it < TPW; ++it) {
        const int tile = waveGlobal * TPW + it;
        const size_t tok0 = (size_t)tile * 64;

        // x -> bf16 A-frags (dtype-adaptive, block-uniform branch)
        short8 xF[4][2];
        if (fx) {
            const unsigned short* xu = (const unsigned short*)x;
            #pragma unroll
            for (int s = 0; s < 4; ++s)
                #pragma unroll
                for (int k = 0; k < 2; ++k)
                    xF[s][k] = *(const short8*)(xu + (tok0 + s * 16 + c) * 64 + k * 32 + q * 8);
        } else {
            const float* xf = (const float*)x;
            #pragma unroll
            for (int s = 0; s < 4; ++s)
                #pragma unroll
                for (int k = 0; k < 2; ++k) {
                    const float* xr = xf + (tok0 + s * 16 + c) * 64 + k * 32 + q * 8;
                    const floatx4 v0 = *(const floatx4*)xr;
                    const floatx4 v1 = *(const floatx4*)(xr + 4);
                    short8 f;
                    #pragma unroll
                    for (int j = 0; j < 4; ++j) { f[j] = f2bf(v0[j]); f[4 + j] = f2bf(v1[j]); }
                    xF[s][k] = f;
                }
        }

        float acc[4][4][4];
        runLayer(xF, 0, acc);

        // h: C-layout fp32 -> bf16 LDS (wave-private) -> A-frags
        short8 hF[4][2];
        #pragma unroll
        for (int s = 0; s < 4; ++s) {
            #pragma unroll
            for (int tt = 0; tt < 4; ++tt)
                #pragma unroll
                for (int r = 0; r < 4; ++r)
                    stg[(4 * q + r) * 72 + tt * 16 + c] = f2bf(acc[s][tt][r]);
            hF[s][0] = *(const short8*)&stg[c * 72 + 0 + q * 8];
            hF[s][1] = *(const short8*)&stg[c * 72 + 32 + q * 8];
        }

        runLayer(hF, 1, acc);

        if (fx) {
            // bf16 out: stage, add residual from x A-frags, coalesced 16B stores
            unsigned short* ob = (unsigned short*)outv;
            #pragma unroll
            for (int s = 0; s < 4; ++s) {
                #pragma unroll
                for (int tt = 0; tt < 4; ++tt)
                    #pragma unroll
                    for (int r = 0; r < 4; ++r)
                        stg[(4 * q + r) * 72 + tt * 16 + c] = f2bf(acc[s][tt][r]);
                #pragma unroll
                for (int k = 0; k < 2; ++k) {
                    const short8 v = *(const short8*)&stg[c * 72 + k * 32 + q * 8];
                    short8 o;
                    #pragma unroll
                    for (int j = 0; j < 8; ++j)
                        o[j] = f2bf(bf2f((unsigned short)v[j]) + bf2f((unsigned short)xF[s][k][j]));
                    *(short8*)(ob + (tok0 + s * 16 + c) * 64 + k * 32 + q * 8) = o;
                }
            }
        } else {
            // fp32 out: stage C-layout -> row-major 16x(stride 68) fp32 in
            // wave-private LDS (2-way max bank aliasing = free), then
            // dwordx4 residual load + dwordx4 store (was 64+64 scalar dwords).
            const float* xf = (const float*)x;
            float* of = (float*)outv;
            #pragma unroll
            for (int s = 0; s < 4; ++s) {
                #pragma unroll
                for (int tt = 0; tt < 4; ++tt)
                    #pragma unroll
                    for (int r = 0; r < 4; ++r)
                        stf[(4 * q + r) * 68 + tt * 16 + c] = acc[s][tt][r];
                // lane owns out-row (tok0+s*16+c), col-block q*16..q*16+15
                const float* srcp = &stf[c * 68 + q * 16];
                const size_t ro = (tok0 + s * 16 + c) * 64 + q * 16;
                #pragma unroll
                for (int jj = 0; jj < 4; ++jj) {
                    const floatx4 v  = *(const floatx4*)(srcp + 4 * jj);
                    const floatx4 xr = *(const floatx4*)(xf + ro + 4 * jj);
                    const floatx4 o  = v + xr;
                    *(floatx4*)(of + ro + 4 * jj) = o;
                }
            }
        }
    }
}

extern "C" void kernel_launch(void* const* d_in, const int* in_sizes, int n_in,
                              void* d_out, int out_size, void* d_ws, size_t ws_size,
                              hipStream_t stream) {
    hipLaunchKernelGGL(moe2_fused, dim3(NBLOCKS), dim3(NTHREADS), 0, stream,
                       d_in[0], d_in[1], d_in[2], d_in[3], d_in[4], d_in[5], d_in[6],
                       d_out);
}

// Round 4
// 343.001 us; speedup vs baseline: 1.2586x; 1.2586x over previous
//
#include <hip/hip_runtime.h>
#include <math.h>

// SPMoEAdaptor: fused 2-layer soft-MoE + residual, N=524288, D=64, E=4.
// out = x + MoE_b(MoE_a(x));  MoE(v) = sum_e softmax(v@Wg)[e] * (v@W_e - b_e@W_e)
//
// R7: revert to the R0 equilibrium (512 blk x 256 thr, launch_bounds(256,2),
// ~104 VGPR, 80.9KB LDS, 2 blocks/CU, NO spills, 190us) after R4-R6 proved
// 1024-thr workgroups always compile to 64 VGPR + ~500MB scratch spill
// traffic on this toolchain (occupancy hints ignored). This round cuts the
// per-tile serial chain instead (R0 was ~75% stall at 2 waves/SIMD):
//  - softmax: 64 ds_bpermute shfl-gathers + redundant all-lane softmax +
//    full fp32 division -> per-lane quad shfl_xor reduce (lanes 0-3 of each
//    16-lane group already hold their expert's logit), exp count /4,
//    v_rcp_f32 instead of div sequence.
//  - gate staged fp32 (floatx4) instead of bf16: kills 128 cvts/tile,
//    better gate precision.
//  - acc update in floatx4 + elementwise_fma -> lets ISel form v_pk_fma_f32.
//  - fp32 epilogue: 64+64 scalar dword VMEM w/ 64-bit addr math -> column-
//    split LDS restage (stride 36 = 16B aligned, <=2-way banks, fits the
//    2304B/wave buffer) -> 16+16 dwordx4 with 32-bit offsets.
//
// DTYPE-ADAPTIVE, in-kernel (no cross-kernel flag handoff): every block
// classifies each input buffer (bf16 vs fp32) by sampling 64 even-indexed
// uint16s; output dtype follows x's dtype. (R0-R3 forensics preserved.)
//
// MFMA 16x16x32_bf16 layouts (m89/m91): A: row=lane&15, k=(lane>>4)*8+j ;
// B: col=lane&15, same k ; C: col=lane&15, row=(lane>>4)*4+reg.

typedef __attribute__((ext_vector_type(8))) short short8;
typedef __attribute__((ext_vector_type(4))) short short4v;
typedef __attribute__((ext_vector_type(4))) float floatx4;

__device__ __forceinline__ float bf2f(unsigned short s) {
    unsigned int u = ((unsigned int)s) << 16;
    return __builtin_bit_cast(float, u);
}
__device__ __forceinline__ short f2bf(float f) {
    unsigned int u = __builtin_bit_cast(unsigned int, f);
    u += 0x7fffu + ((u >> 16) & 1u);   // RNE
    return (short)(u >> 16);
}
__device__ __forceinline__ float fastrcp(float x) {
#if __has_builtin(__builtin_amdgcn_rcpf)
    return __builtin_amdgcn_rcpf(x);
#else
    return 1.f / x;
#endif
}

#define NBLOCKS 512
#define TPW 4   // tiles (of 64 tokens) per wave: 512*4*4*64 = 524288

__device__ __forceinline__ float ldf(const void* p, int isbf, int idx) {
    return isbf ? bf2f(((const unsigned short*)p)[idx]) : ((const float*)p)[idx];
}

__global__ __launch_bounds__(256, 2)
void moe2_fused(const void* __restrict__ x,
                const void* __restrict__ wg_a,
                const void* __restrict__ we_a,
                const void* __restrict__ be_a,
                const void* __restrict__ wg_b,
                const void* __restrict__ we_b,
                const void* __restrict__ be_b,
                void* __restrict__ outv)
{
    __shared__ alignas(16) short sB[2][17408];     // weights, fragment-major bf16 (69632 B)
    __shared__ float sC[2][4][64];                 // c_e[f] = b_e @ W_e (2048 B)
    __shared__ alignas(16) short sStage[4][1152];  // per-wave scratch 2304 B
    __shared__ int sBad[7];

    const int tid = threadIdx.x;

    // ---- in-block dtype classification (ballot-free, 256B/buffer) ----
    const void* ps[7] = {x, wg_a, we_a, be_a, wg_b, we_b, be_b};
    if (tid < 7) sBad[tid] = 0;
    __syncthreads();
    if (tid < 64) {
        #pragma unroll
        for (int b = 0; b < 7; ++b) {
            const unsigned short s = ((const unsigned short*)ps[b])[2 * tid];
            const float a = fabsf(bf2f(s));
            const bool sane = (s == 0) || (a >= 9.3e-10f && a <= 1.1e9f);
            if (!sane) atomicAdd(&sBad[b], 1);
        }
    }
    __syncthreads();
    const int fx  = (sBad[0] < 16);
    const int fga = (sBad[1] < 16), fwa = (sBad[2] < 16), fba = (sBad[3] < 16);
    const int fgb = (sBad[4] < 16), fwb = (sBad[5] < 16), fbb = (sBad[6] < 16);

    // ---- stage weights into LDS (-> bf16), fragment-major ----
    for (int idx = tid; idx < 2 * 17 * 2 * 64; idx += 256) {
        const int L   = idx / 2176;
        const int rem = idx - L * 2176;        // (t*2+kap)*64 + lane
        const int t   = rem >> 7;
        const int kap = (rem >> 6) & 1;
        const int l2  = rem & 63;
        const int kb  = kap * 32 + (l2 >> 4) * 8;
        const int cc  = l2 & 15;
        const void* we = L ? we_b : we_a;
        const void* wg = L ? wg_b : wg_a;
        const int  fwe = L ? fwb : fwa;
        const int  fwg = L ? fgb : fga;
        short* dst = &sB[L][rem * 8];
        if (t < 16) {
            const int e = t >> 2;
            const int f = (t & 3) * 16 + cc;
            #pragma unroll
            for (int j = 0; j < 8; ++j)
                dst[j] = f2bf(ldf(we, fwe, (e * 64 + kb + j) * 64 + f));  // w_exp[e][k][f]
        } else {  // gate tile: cols 0..3 = Wg, rest zero
            #pragma unroll
            for (int j = 0; j < 8; ++j)
                dst[j] = (cc < 4) ? f2bf(ldf(wg, fwg, (kb + j) * 4 + cc)) : (short)0;
        }
    }
    // ---- c_e[f] = sum_d b_e[d] * W_e[d][f] (fp32) ----
    for (int idx = tid; idx < 512; idx += 256) {
        const int L = idx >> 8;
        const int e = (idx >> 6) & 3;
        const int f = idx & 63;
        const void* we = L ? we_b : we_a;
        const void* be = L ? be_b : be_a;
        const int  fwe = L ? fwb : fwa;
        const int  fbe = L ? fbb : fba;
        float s = 0.f;
        for (int d = 0; d < 64; ++d)
            s += ldf(be, fbe, e * 64 + d) * ldf(we, fwe, (e * 64 + d) * 64 + f);
        sC[L][e][f] = s;
    }
    __syncthreads();

    const int l  = tid & 63;
    const int wv = tid >> 6;
    const int c  = l & 15;   // C-layout col AND A-layout row for this lane
    const int q  = l >> 4;
    short* stg  = &sStage[wv][0];        // wave-private bf16 view (h restage)
    float* gstg = (float*)&sStage[wv][0]; // wave-private fp32 view (gate, epilogue)

    auto runLayer = [&](const short8 (&aF)[4][2], const int L, floatx4 (&acc)[4][4]) {
        const short* BL = &sB[L][0];
        floatx4 gA[4];
        {
            const short8 B0 = *(const short8*)&BL[(16 * 2 + 0) * 512 + l * 8];
            const short8 B1 = *(const short8*)&BL[(16 * 2 + 1) * 512 + l * 8];
            #pragma unroll
            for (int s = 0; s < 4; ++s) {
                floatx4 z = {0.f, 0.f, 0.f, 0.f};
                z = __builtin_amdgcn_mfma_f32_16x16x32_bf16(aF[s][0], B0, z, 0, 0, 0);
                z = __builtin_amdgcn_mfma_f32_16x16x32_bf16(aF[s][1], B1, z, 0, 0, 0);
                gA[s] = z;
            }
        }
        // per-lane softmax: lane (c,q) holds logit[row 4q+r][expert c] (c<4;
        // cols 4..15 are exact zeros from the padded gate tile -> harmless).
        // Quad shfl_xor (xor1, xor2) reduces over the 4 experts in-place.
        #pragma unroll
        for (int s = 0; s < 4; ++s) {
            floatx4 g4;
            #pragma unroll
            for (int r = 0; r < 4; ++r) {
                const float v = gA[s][r];
                float m = fmaxf(v, __shfl_xor(v, 1, 64));
                m = fmaxf(m, __shfl_xor(m, 2, 64));
                const float ev = __expf(v - m);
                float sm = ev + __shfl_xor(ev, 1, 64);
                sm += __shfl_xor(sm, 2, 64);
                g4[r] = ev * fastrcp(sm);
            }
            if (c < 4) *(floatx4*)&gstg[(s * 4 + c) * 16 + 4 * q] = g4;
        }

        #pragma unroll
        for (int s = 0; s < 4; ++s)
            #pragma unroll
            for (int tt = 0; tt < 4; ++tt)
                acc[s][tt] = (floatx4){0.f, 0.f, 0.f, 0.f};

        #pragma unroll
        for (int e = 0; e < 4; ++e) {
            floatx4 ge[4];
            #pragma unroll
            for (int s = 0; s < 4; ++s)
                ge[s] = *(const floatx4*)&gstg[(s * 4 + e) * 16 + 4 * q];
            #pragma unroll
            for (int tt = 0; tt < 4; ++tt) {
                const int t = e * 4 + tt;
                const short8 B0 = *(const short8*)&BL[(t * 2 + 0) * 512 + l * 8];
                const short8 B1 = *(const short8*)&BL[(t * 2 + 1) * 512 + l * 8];
                const float ce = sC[L][e][tt * 16 + c];
                const floatx4 cv = {ce, ce, ce, ce};
                #pragma unroll
                for (int s = 0; s < 4; ++s) {
                    floatx4 z = {0.f, 0.f, 0.f, 0.f};
                    z = __builtin_amdgcn_mfma_f32_16x16x32_bf16(aF[s][0], B0, z, 0, 0, 0);
                    z = __builtin_amdgcn_mfma_f32_16x16x32_bf16(aF[s][1], B1, z, 0, 0, 0);
                    acc[s][tt] = __builtin_elementwise_fma(ge[s], z - cv, acc[s][tt]);
                }
            }
        }
    };

    const int waveGlobal = blockIdx.x * 4 + wv;
    for (int it = 0; it < TPW; ++it) {
        const int tile = waveGlobal * TPW + it;
        const unsigned tok0 = (unsigned)tile * 64u;

        // x -> bf16 A-frags (dtype-adaptive, block-uniform branch)
        short8 xF[4][2];
        if (fx) {
            const unsigned short* xu = (const unsigned short*)x;
            #pragma unroll
            for (int s = 0; s < 4; ++s)
                #pragma unroll
                for (int k = 0; k < 2; ++k)
                    xF[s][k] = *(const short8*)(xu + (tok0 + s * 16 + c) * 64u + k * 32 + q * 8);
        } else {
            const float* xf = (const float*)x;
            #pragma unroll
            for (int s = 0; s < 4; ++s)
                #pragma unroll
                for (int k = 0; k < 2; ++k) {
                    const float* xr = xf + (tok0 + s * 16 + c) * 64u + k * 32 + q * 8;
                    const floatx4 v0 = *(const floatx4*)xr;
                    const floatx4 v1 = *(const floatx4*)(xr + 4);
                    short8 f;
                    #pragma unroll
                    for (int j = 0; j < 4; ++j) { f[j] = f2bf(v0[j]); f[4 + j] = f2bf(v1[j]); }
                    xF[s][k] = f;
                }
        }

        floatx4 acc[4][4];
        runLayer(xF, 0, acc);

        // h: C-layout fp32 -> bf16 LDS (wave-private) -> A-frags
        short8 hF[4][2];
        #pragma unroll
        for (int s = 0; s < 4; ++s) {
            #pragma unroll
            for (int tt = 0; tt < 4; ++tt)
                #pragma unroll
                for (int r = 0; r < 4; ++r)
                    stg[(4 * q + r) * 72 + tt * 16 + c] = f2bf(acc[s][tt][r]);
            hF[s][0] = *(const short8*)&stg[c * 72 + 0 + q * 8];
            hF[s][1] = *(const short8*)&stg[c * 72 + 32 + q * 8];
        }

        runLayer(hF, 1, acc);

        if (fx) {
            // bf16 out: stage, add residual from x A-frags, coalesced 16B stores
            unsigned short* ob = (unsigned short*)outv;
            #pragma unroll
            for (int s = 0; s < 4; ++s) {
                #pragma unroll
                for (int tt = 0; tt < 4; ++tt)
                    #pragma unroll
                    for (int r = 0; r < 4; ++r)
                        stg[(4 * q + r) * 72 + tt * 16 + c] = f2bf(acc[s][tt][r]);
                #pragma unroll
                for (int k = 0; k < 2; ++k) {
                    const short8 v = *(const short8*)&stg[c * 72 + k * 32 + q * 8];
                    short8 o;
                    #pragma unroll
                    for (int j = 0; j < 8; ++j)
                        o[j] = f2bf(bf2f((unsigned short)v[j]) + bf2f((unsigned short)xF[s][k][j]));
                    *(short8*)(ob + (tok0 + s * 16 + c) * 64u + k * 32 + q * 8) = o;
                }
            }
        } else {
            // fp32 out: column-split restage. Per (s, half): stage 16 rows x
            // 32 cols fp32 at stride 36 (16x36x4 = 2304B = wave buffer;
            // 144B rows keep dwordx4 alignment; banks <=2-way), then
            // dwordx4 residual load + dwordx4 store with 32-bit offsets.
            const float* xf = (const float*)x;
            float* of = (float*)outv;
            #pragma unroll
            for (int s = 0; s < 4; ++s) {
                #pragma unroll
                for (int H = 0; H < 2; ++H) {
                    #pragma unroll
                    for (int t2 = 0; t2 < 2; ++t2)
                        #pragma unroll
                        for (int r = 0; r < 4; ++r)
                            gstg[(4 * q + r) * 36 + t2 * 16 + c] = acc[s][H * 2 + t2][r];
                    // lane owns out-row (tok0+s*16+c), cols H*32+q*8 .. +7
                    const float* srcp = &gstg[c * 36 + q * 8];
                    const unsigned ro = (tok0 + s * 16 + c) * 64u + H * 32 + q * 8;
                    const floatx4 v0 = *(const floatx4*)(srcp);
                    const floatx4 v1 = *(const floatx4*)(srcp + 4);
                    const floatx4 x0 = *(const floatx4*)(xf + ro);
                    const floatx4 x1 = *(const floatx4*)(xf + ro + 4);
                    *(floatx4*)(of + ro)     = v0 + x0;
                    *(floatx4*)(of + ro + 4) = v1 + x1;
                }
            }
        }
    }
}

extern "C" void kernel_launch(void* const* d_in, const int* in_sizes, int n_in,
                              void* d_out, int out_size, void* d_ws, size_t ws_size,
                              hipStream_t stream) {
    hipLaunchKernelGGL(moe2_fused, dim3(NBLOCKS), dim3(256), 0, stream,
                       d_in[0], d_in[1], d_in[2], d_in[3], d_in[4], d_in[5], d_in[6],
                       d_out);
}